// Round 9
// baseline (111.399 us; speedup 1.0000x reference)
//
#include <hip/hip_runtime.h>
#include <hip/hip_bf16.h>

// DispCorrLayer: out[b,d,h,w] = (1/C) * sum_c in1[b,c,h,w] * in2[b,c,h,w-(D-d)]
// (zero when w + d < D). B=4 C=32 H=256 W=512 D=128, fp32.
//
// R9 = R8 (banded-GEMM MFMA + LDS diagonal-transpose epilogue) with:
//  - ob XOR-quad swizzle: scatter addr 20d + 4*(rg^(d&3)) + q -> ~4-way banks
//    (was structurally 8-way); scatter addresses reduce to per-lane constants
//    bq[q] + 320*mm (folded into ds-offset immediates).
//  - all MFMA fragments preloaded per wave (bfr[12] sliding window + afr[4]):
//    16 b128 frag reads/wave instead of 40.
//  - bf16 pack via compiler __float22bfloat162_rn (RNE, same numerics),
//    ~4x fewer VALU ops than manual pack2.
//  - nontemporal loads for block-exclusive in1; nt stores kept.

#define BB 4
#define CC 32
#define HH 256
#define WW 512
#define DD 128
#define HW (HH * WW)

#define NT 256               // 4 waves
#define WHALF 256            // w span per block
#define S2N 384              // staged in2 cols: w' in [wb-128, wb+256)
#define OBS 20               // ob row stride (words)

typedef __attribute__((ext_vector_type(8))) short bf16x8;
typedef __attribute__((ext_vector_type(4))) float f32x4;

__device__ __forceinline__ unsigned int pk(float lo, float hi) {
    union { __hip_bfloat162 h; unsigned int u; } z;
    z.h = __float22bfloat162_rn(make_float2(lo, hi));
    return z.u;
}

// word index of the 16B chunk holding row `row`, k-chunk `kc` (8 bf16).
__device__ __forceinline__ int cidx(int row, int kc) {
    return (row * 4 + (kc ^ ((row >> 1) & 3))) * 4;
}

__global__ __launch_bounds__(NT, 2)
void disp_corr_kernel(const float* __restrict__ in1,
                      const float* __restrict__ in2,
                      float* __restrict__ out) {
    __shared__ __align__(16) unsigned int s1t[WHALF * 16];  // in1^T bf16, 16 KB
    __shared__ __align__(16) unsigned int s2t[S2N * 16];    // in2^T bf16, 24 KB
    __shared__ __align__(16) float ob[4][DD * OBS];         // band buf, 40 KB

    const int t = threadIdx.x;

    // XCD swizzle (bijective, 2048 = 8*256)
    const int xcd = blockIdx.x & 7, slot = blockIdx.x >> 3;
    const int work = (xcd << 8) + slot;
    const int wh = work & 1;
    const int h  = (work >> 1) & (HH - 1);
    const int b  = work >> 9;
    const int wb = wh * WHALF;

    const float* p1 = in1 + (size_t)b * CC * HW + (size_t)h * WW + wb;
    const float* p2 = in2 + (size_t)b * CC * HW + (size_t)h * WW;

    // ---- staging: thread t owns col t (s1t, s2t row t) and s2t row 256+t ----
    const float sc = 1.0f / (float)CC;
    float v1[CC], v2[CC], v3[CC];
    #pragma unroll
    for (int c = 0; c < CC; ++c)
        v1[c] = __builtin_nontemporal_load(p1 + (size_t)c * HW + t);
    const int wp0 = wb + t - DD;
    if (wp0 >= 0) {
        #pragma unroll
        for (int c = 0; c < CC; ++c) v2[c] = p2[(size_t)c * HW + wp0];
    } else {
        #pragma unroll
        for (int c = 0; c < CC; ++c) v2[c] = 0.f;
    }
    const bool rep1 = (t < S2N - NT);                // t < 128
    const int wp1 = wb + DD + t;                     // in [128, 512)
    if (rep1) {
        #pragma unroll
        for (int c = 0; c < CC; ++c) v3[c] = p2[(size_t)c * HW + wp1];
    }

    #pragma unroll
    for (int kc = 0; kc < 4; ++kc) {
        unsigned int u[4];
        #pragma unroll
        for (int ci = 0; ci < 4; ++ci)
            u[ci] = pk(v1[kc * 8 + 2 * ci] * sc, v1[kc * 8 + 2 * ci + 1] * sc);
        *(uint4*)&s1t[cidx(t, kc)] = make_uint4(u[0], u[1], u[2], u[3]);
    }
    #pragma unroll
    for (int kc = 0; kc < 4; ++kc) {
        unsigned int u[4];
        #pragma unroll
        for (int ci = 0; ci < 4; ++ci)
            u[ci] = pk(v2[kc * 8 + 2 * ci], v2[kc * 8 + 2 * ci + 1]);
        *(uint4*)&s2t[cidx(t, kc)] = make_uint4(u[0], u[1], u[2], u[3]);
    }
    if (rep1) {
        #pragma unroll
        for (int kc = 0; kc < 4; ++kc) {
            unsigned int u[4];
            #pragma unroll
            for (int ci = 0; ci < 4; ++ci)
                u[ci] = pk(v3[kc * 8 + 2 * ci], v3[kc * 8 + 2 * ci + 1]);
            *(uint4*)&s2t[cidx(NT + t, kc)] = make_uint4(u[0], u[1], u[2], u[3]);
        }
    }
    __syncthreads();

    // ---- compute: wave wv owns w-tiles i0..i0+3; all frags preloaded ----
    const int lane = t & 63;
    const int wv   = t >> 6;
    const int cl   = lane & 15;       // fragment col (w' within tile)
    const int rg   = lane >> 4;       // fragment row group (w)
    float* myob = ob[wv];
    const size_t obase = (size_t)b * DD * HW + (size_t)h * WW + wb;
    const int i0 = wv * 4;

    uint4 afr[4], bfr[12];
    #pragma unroll
    for (int m = 0; m < 12; ++m)
        bfr[m] = *(const uint4*)&s2t[cidx((i0 + m) * 16 + cl, rg)];
    #pragma unroll
    for (int ii = 0; ii < 4; ++ii)
        afr[ii] = *(const uint4*)&s1t[cidx((i0 + ii) * 16 + cl, rg)];

    // scatter bases: idx(mm,q) = bq[q] + 320*mm (tile-invariant)
    int bq[4];
    #pragma unroll
    for (int q = 0; q < 4; ++q)
        bq[q] = 20 * (cl - 4 * rg - q) + 4 * (rg ^ ((cl - q) & 3)) + q;

    const int dq  = lane >> 2;        // store phase: d within 16-group
    const int j   = lane & 3;         // store phase: read-quad
    const int jx4 = 4 * (j ^ (dq & 3));   // un-swizzled target quad

    #pragma unroll
    for (int ii = 0; ii < 4; ++ii) {
        const int i = i0 + ii;                     // local w-tile 0..15
        #pragma unroll
        for (int mm = 0; mm <= 8; ++mm) {
            union { uint4 u; bf16x8 v; } a, bb;
            a.u  = afr[ii];
            bb.u = bfr[ii + mm];
            f32x4 acc = {0.f, 0.f, 0.f, 0.f};
            acc = __builtin_amdgcn_mfma_f32_16x16x32_bf16(a.v, bb.v, acc, 0, 0, 0);
            #pragma unroll
            for (int q = 0; q < 4; ++q) {
                const int rq = 4 * rg + q;
                const bool ok = (mm == 0) ? (cl >= rq)
                              : (mm == 8) ? (cl < rq) : true;
                if (ok) myob[bq[q] + 320 * mm] = acc[q];
            }
        }
        // coalesced store: per dg, 16 d-planes x one full 64B line each
        #pragma unroll
        for (int dg = 0; dg < 8; ++dg) {
            const int d = dg * 16 + dq;
            f32x4 v = *(const f32x4*)&myob[d * OBS + 4 * j];
            __builtin_nontemporal_store(
                v, (f32x4*)(out + obase + (size_t)d * HW + i * 16 + jx4));
        }
    }
}

extern "C" void kernel_launch(void* const* d_in, const int* in_sizes, int n_in,
                              void* d_out, int out_size, void* d_ws, size_t ws_size,
                              hipStream_t stream) {
    const float* in1 = (const float*)d_in[0];
    const float* in2 = (const float*)d_in[1];
    float* out = (float*)d_out;
    const int nblocks = BB * HH * 2;             // 2048
    disp_corr_kernel<<<nblocks, NT, 0, stream>>>(in1, in2, out);
}

// Round 10
// 91.741 us; speedup vs baseline: 1.2143x; 1.2143x over previous
//
#include <hip/hip_runtime.h>

// DispCorrLayer: out[b,d,h,w] = (1/C) * sum_c in1[b,c,h,w] * in2[b,c,h,w-(D-d)]
// (zero when w + d < D). B=4 C=32 H=256 W=512 D=128, fp32.
//
// R10 = R8 (banded-GEMM MFMA + LDS diagonal-transpose epilogue, OBS=20,
// folded 1/32 scale, nt stores) + two-level XOR scatter swizzle:
//   scatter word addr = 20d + 4*(rg^(d&3)) + (q^((d>>4)&3))
//  - low-2-bit XOR varies per lane -> breaks R8's structural 8-way conflict
//    (addr mod 4 was pinned to q) down to ~2-3-way.
//  - readback: d>>4 = dg (static per unrolled iteration) -> slot un-permute
//    is a compile-time component relabel; quad un-permute folds into the
//    per-lane read address. Global stores stay monotone (R8-identical).

#define BB 4
#define CC 32
#define HH 256
#define WW 512
#define DD 128
#define HW (HH * WW)

#define NT 256               // 4 waves
#define WHALF 256            // w span per block
#define S2N 384              // staged in2 cols: w' in [wb-128, wb+256)
#define OBS 20               // ob row stride (words): 16B-aligned rows

typedef __attribute__((ext_vector_type(8))) short bf16x8;
typedef __attribute__((ext_vector_type(4))) float f32x4;

__device__ __forceinline__ unsigned int pack2(float a, float b) {
    // RNE bf16 round: a -> low half, b -> high half
    union { float f; unsigned int i; } x, y; x.f = a; y.f = b;
    unsigned int xi = x.i + 0x7fffu + ((x.i >> 16) & 1u);
    unsigned int yi = y.i + 0x7fffu + ((y.i >> 16) & 1u);
    return (xi >> 16) | (yi & 0xffff0000u);
}

// word index of the 16B chunk holding row `row`, k-chunk `kc` (8 bf16).
__device__ __forceinline__ int cidx(int row, int kc) {
    return (row * 4 + (kc ^ ((row >> 1) & 3))) * 4;
}

__global__ __launch_bounds__(NT, 2)
void disp_corr_kernel(const float* __restrict__ in1,
                      const float* __restrict__ in2,
                      float* __restrict__ out) {
    __shared__ __align__(16) unsigned int s1t[WHALF * 16];  // in1^T bf16, 16 KB
    __shared__ __align__(16) unsigned int s2t[S2N * 16];    // in2^T bf16, 24 KB
    __shared__ __align__(16) float ob[4][DD * OBS];         // band buf, 40 KB

    const int t = threadIdx.x;

    // XCD swizzle (bijective, 2048 = 8*256)
    const int xcd = blockIdx.x & 7, slot = blockIdx.x >> 3;
    const int work = (xcd << 8) + slot;
    const int wh = work & 1;
    const int h  = (work >> 1) & (HH - 1);
    const int b  = work >> 9;
    const int wb = wh * WHALF;

    const float* p1 = in1 + (size_t)b * CC * HW + (size_t)h * WW + wb;
    const float* p2 = in2 + (size_t)b * CC * HW + (size_t)h * WW;

    // ---- issue ALL staging loads first ----
    const float sc = 1.0f / (float)CC;
    float v1[CC], v2[CC], v3[CC];
    #pragma unroll
    for (int c = 0; c < CC; ++c) v1[c] = p1[(size_t)c * HW + t];
    const int wp0 = wb + t - DD;
    if (wp0 >= 0) {
        #pragma unroll
        for (int c = 0; c < CC; ++c) v2[c] = p2[(size_t)c * HW + wp0];
    } else {
        #pragma unroll
        for (int c = 0; c < CC; ++c) v2[c] = 0.f;
    }
    const bool rep1 = (t < S2N - NT);                // t < 128
    const int wp1 = wb + DD + t;                     // in [128, 512)
    if (rep1) {
        #pragma unroll
        for (int c = 0; c < CC; ++c) v3[c] = p2[(size_t)c * HW + wp1];
    }

    // ---- pack + commit to LDS ----
    #pragma unroll
    for (int kc = 0; kc < 4; ++kc) {
        unsigned int u[4];
        #pragma unroll
        for (int ci = 0; ci < 4; ++ci)
            u[ci] = pack2(v1[kc * 8 + 2 * ci] * sc, v1[kc * 8 + 2 * ci + 1] * sc);
        *(uint4*)&s1t[cidx(t, kc)] = make_uint4(u[0], u[1], u[2], u[3]);
    }
    #pragma unroll
    for (int kc = 0; kc < 4; ++kc) {
        unsigned int u[4];
        #pragma unroll
        for (int ci = 0; ci < 4; ++ci)
            u[ci] = pack2(v2[kc * 8 + 2 * ci], v2[kc * 8 + 2 * ci + 1]);
        *(uint4*)&s2t[cidx(t, kc)] = make_uint4(u[0], u[1], u[2], u[3]);
    }
    if (rep1) {
        #pragma unroll
        for (int kc = 0; kc < 4; ++kc) {
            unsigned int u[4];
            #pragma unroll
            for (int ci = 0; ci < 4; ++ci)
                u[ci] = pack2(v3[kc * 8 + 2 * ci], v3[kc * 8 + 2 * ci + 1]);
            *(uint4*)&s2t[cidx(NT + t, kc)] = make_uint4(u[0], u[1], u[2], u[3]);
        }
    }
    __syncthreads();

    // ---- per wave: 4 w-tiles; per tile: 9 MFMA -> ob scatter -> b128 store ----
    const int lane = t & 63;
    const int wv   = t >> 6;
    const int cl   = lane & 15;       // fragment col (w' within tile)
    const int rg   = lane >> 4;       // fragment row group (w)
    float* myob = ob[wv];
    const size_t obase = (size_t)b * DD * HW + (size_t)h * WW + wb;

    // scatter precompute: e = cl-4rg; per q: base (sans slot-XOR) + cge flag
    const int e = cl - 4 * rg;
    int pb[4];
    bool cge[4];
    #pragma unroll
    for (int q = 0; q < 4; ++q) {
        pb[q]  = 20 * (e - q) + 4 * (rg ^ ((cl - q) & 3));
        cge[q] = (e >= q);
    }

    const int dq  = lane >> 2;        // store phase: d within 16-group
    const int j   = lane & 3;         // store phase: output w-quad
    const int jxr = j ^ (dq & 3);     // swizzled read-quad position

    #pragma unroll
    for (int ii = 0; ii < 4; ++ii) {
        const int i = wv * 4 + ii;                 // local w-tile 0..15
        union { uint4 u; bf16x8 v; } a;
        a.u = *(const uint4*)&s1t[cidx(i * 16 + cl, rg)];
        #pragma unroll
        for (int mm = 0; mm <= 8; ++mm) {
            union { uint4 u; bf16x8 v; } bq;
            bq.u = *(const uint4*)&s2t[cidx((i + mm) * 16 + cl, rg)];
            f32x4 acc = {0.f, 0.f, 0.f, 0.f};
            acc = __builtin_amdgcn_mfma_f32_16x16x32_bf16(a.v, bq.v, acc, 0, 0, 0);
            // d = 16mm + cl - (4rg+q); slot-XOR g = (d>>4)&3 = mm or mm-1
            #pragma unroll
            for (int q = 0; q < 4; ++q) {
                const bool ok = (mm == 0) ? cge[q]
                              : (mm == 8) ? !cge[q] : true;
                const int sA = q ^ (mm & 3);            // cl >= r
                const int sB = q ^ ((mm - 1) & 3);      // cl <  r
                const int addr = pb[q] + 320 * mm + (cge[q] ? sA : sB);
                if (ok) myob[addr] = acc[q];
            }
        }
        // coalesced store: per dg, 16 d-planes x one full 64B line each
        #pragma unroll
        for (int dg = 0; dg < 8; ++dg) {
            const int d = dg * 16 + dq;
            const int f = dg & 3;                  // static slot un-permute
            f32x4 v = *(const f32x4*)&myob[d * OBS + 4 * jxr];
            f32x4 w;
            w[0] = v[0 ^ f]; w[1] = v[1 ^ f];
            w[2] = v[2 ^ f]; w[3] = v[3 ^ f];
            __builtin_nontemporal_store(
                w, (f32x4*)(out + obase + (size_t)d * HW + i * 16 + 4 * j));
        }
    }
}

extern "C" void kernel_launch(void* const* d_in, const int* in_sizes, int n_in,
                              void* d_out, int out_size, void* d_ws, size_t ws_size,
                              hipStream_t stream) {
    const float* in1 = (const float*)d_in[0];
    const float* in2 = (const float*)d_in[1];
    float* out = (float*)d_out;
    const int nblocks = BB * HH * 2;             // 2048
    disp_corr_kernel<<<nblocks, NT, 0, stream>>>(in1, in2, out);
}